// Round 8
// baseline (209.639 us; speedup 1.0000x reference)
//
#include <hip/hip_runtime.h>
#include <hip/hip_fp16.h>
#include <math.h>

typedef unsigned int u32;
typedef unsigned short u16;

#define T_ 16
#define B_ 32
#define S_ 256
#define H_ 256
#define E_ 300
#define V_ 1000

typedef _Float16 h2_t __attribute__((ext_vector_type(2)));
typedef __fp16  fp16v2 __attribute__((ext_vector_type(2)));

__device__ __forceinline__ float fast_tanh(float x) {
    return 1.0f - 2.0f / (__expf(2.0f * x) + 1.0f);
}
__device__ __forceinline__ float fast_sigm(float x) {
    return 1.0f / (1.0f + __expf(-x));
}
__device__ __forceinline__ float blo(u32 u) { return __uint_as_float(u << 16); }
__device__ __forceinline__ float bhi(u32 u) { return __uint_as_float(u & 0xffff0000u); }
__device__ __forceinline__ h2_t u2h2(u32 u) {
    union { u32 a; h2_t b; } c; c.a = u; return c.b;
}
__device__ __forceinline__ u32 pk2(float a, float b) {
    union { fp16v2 v; u32 u; } c; c.v = __builtin_amdgcn_cvt_pkrtz(a, b); return c.u;
}
__device__ __forceinline__ float dot2f16(u32 w, u32 h, float acc) {
#if __has_builtin(__builtin_amdgcn_fdot2)
    return __builtin_amdgcn_fdot2(u2h2(w), u2h2(h), acc, false);
#else
    h2_t wv = u2h2(w), hv = u2h2(h);
    return acc + (float)wv.x * (float)hv.x + (float)wv.y * (float)hv.y;
#endif
}

// ---------------------------------------------------------------------------
// Kernel 1: prep v6 (round-7 proven) — xproj GEMM 32x64 tiles + Whh->Wt2.
// ---------------------------------------------------------------------------
__global__ __launch_bounds__(256)
void prep_xproj(const float* __restrict__ emb, const int* __restrict__ tv,
                const float* __restrict__ W_ih, const float* __restrict__ b_ih,
                float* __restrict__ xproj,
                const float* __restrict__ Whh,  u32* __restrict__ Wt2)
{
    const int bid = blockIdx.x;
    const int tid = threadIdx.x;
    if (bid < 256) {
        __shared__ float As[32][33];
        __shared__ float Bs[32][64];
        const int bm = (bid >> 4) * 32;
        const int bn = (bid & 15) * 64;
        const int ty = tid >> 4;
        const int tx = tid & 15;
        const int alr = tid >> 3;
        const int alk = (tid & 7) * 4;
        const int blr = tid >> 2;
        const int blk = (tid & 3) * 8;

        const float* Ap = emb + (size_t)tv[bm + alr] * E_;
        const float* Bp = W_ih + (size_t)(bn + blr) * E_;

        float acc[2][4] = {};
        for (int k0 = 0; k0 < E_; k0 += 32) {
            int kb = k0 + alk;
            float4 a4;
            if (kb + 4 <= E_) {
                a4 = *(const float4*)(Ap + kb);
            } else {
                a4.x = (kb + 0 < E_) ? Ap[kb + 0] : 0.0f;
                a4.y = (kb + 1 < E_) ? Ap[kb + 1] : 0.0f;
                a4.z = (kb + 2 < E_) ? Ap[kb + 2] : 0.0f;
                a4.w = (kb + 3 < E_) ? Ap[kb + 3] : 0.0f;
            }
            As[alk + 0][alr] = a4.x; As[alk + 1][alr] = a4.y;
            As[alk + 2][alr] = a4.z; As[alk + 3][alr] = a4.w;

            int kbb = k0 + blk;
            float bv[8];
            if (kbb + 8 <= E_) {
                float4 p0 = *(const float4*)(Bp + kbb);
                float4 p1 = *(const float4*)(Bp + kbb + 4);
                bv[0]=p0.x; bv[1]=p0.y; bv[2]=p0.z; bv[3]=p0.w;
                bv[4]=p1.x; bv[5]=p1.y; bv[6]=p1.z; bv[7]=p1.w;
            } else {
                #pragma unroll
                for (int j = 0; j < 8; j++) bv[j] = (kbb + j < E_) ? Bp[kbb + j] : 0.0f;
            }
            #pragma unroll
            for (int j = 0; j < 8; j++) Bs[blk + j][blr] = bv[j];
            __syncthreads();
            #pragma unroll
            for (int kk = 0; kk < 32; kk++) {
                float ax = As[kk][ty * 2], ay = As[kk][ty * 2 + 1];
                float4 b = *(const float4*)&Bs[kk][tx * 4];
                acc[0][0] += ax*b.x; acc[0][1] += ax*b.y; acc[0][2] += ax*b.z; acc[0][3] += ax*b.w;
                acc[1][0] += ay*b.x; acc[1][1] += ay*b.y; acc[1][2] += ay*b.z; acc[1][3] += ay*b.w;
            }
            __syncthreads();
        }
        #pragma unroll
        for (int i = 0; i < 2; i++) {
            int m = bm + ty * 2 + i;
            #pragma unroll
            for (int j = 0; j < 4; j++) {
                int n = bn + tx * 4 + j;
                xproj[(size_t)m * 1024 + n] = acc[i][j] + b_ih[n];
            }
        }
        return;
    }
    // Whh transpose -> Wt2 uint4 [32][1024] (f16 pairs), bids 256..319
    __shared__ float tile[64][65];
    const int wv = tid >> 6;
    const int lane = tid & 63;
    int t = bid - 256;
    int r0 = (t >> 2) * 64, k0 = (t & 3) * 64;
    #pragma unroll 4
    for (int j = 0; j < 16; j++) {
        int row = wv * 16 + j;
        tile[row][lane] = Whh[(size_t)(r0 + row) * 256 + k0 + lane];
    }
    __syncthreads();
    #pragma unroll
    for (int it = 0; it < 2; it++) {
        int q = wv + 4 * it;
        uint4 val;
        val.x = pk2(tile[lane][8*q + 0], tile[lane][8*q + 1]);
        val.y = pk2(tile[lane][8*q + 2], tile[lane][8*q + 3]);
        val.z = pk2(tile[lane][8*q + 4], tile[lane][8*q + 5]);
        val.w = pk2(tile[lane][8*q + 6], tile[lane][8*q + 7]);
        ((uint4*)Wt2)[(size_t)((k0 >> 3) + q) * 1024 + r0 + lane] = val;
    }
}

// ---------------------------------------------------------------------------
// Kernel 2: lstm + enc_t + Wd/Wout transposes (round-7 proven body;
// waves_per_eu(4,4) keeps wreg[16] unspilled). Round-8 change: the W_out
// transpose now emits WoT2 f16-PAIR layout (uint4 [64 kq8][1000 v], elem =
// k=8*kq8..+7 packed as 4 f16-pairs for vocab v) so attn's vocab loop can
// use fdot2 (2 MAC/instr, no unpack) instead of bf16 blo/bhi.
//   bid 32..159 : enc_t 128x128 tile
//   bid 160..175: Wd transpose (fp32, unchanged)
//   bid 176..303: W_out -> WoT2 f16-pair transpose
// ---------------------------------------------------------------------------
__global__ __launch_bounds__(1024)
__attribute__((amdgpu_waves_per_eu(4, 4)))
void lstm_enct(const float* __restrict__ xproj,   // [T,B,1024]
               const u32*   __restrict__ Wt2,     // uint4 [32][1024]
               const float* __restrict__ bhh,     // [1024]
               const float* __restrict__ h0, const float* __restrict__ c0,
               float* __restrict__ combined,      // [T,B,512] second half
               float* __restrict__ hT, float* __restrict__ cT,
               const float* __restrict__ enc_raw, // [8192,256]
               const float* __restrict__ We,      // [256,256]
               const float* __restrict__ be,
               float* __restrict__ enct,          // [8192,256]
               const float* __restrict__ Wd,   float* __restrict__ Wdt,
               const float* __restrict__ W_out, u32* __restrict__ WoT2)
{
    const int bid = blockIdx.x;
    const int tid = threadIdx.x;
    __shared__ __align__(16) u32 smem[38272];

    if (bid < 32) {
        float* zs = (float*)smem;            // [1024]
        float* cs = (float*)(smem + 1024);   // [256]
        u32*   hp = smem + 1280;             // [128]
        u32*   wlds = smem + 1408;           // [32][1024] dword-sliced (8 groups)
        float* hsave = (float*)(smem + 34176); // [16][256]
        const int b = bid;
        const int r = tid;
        if (tid < 256) {
            float h0v = h0[b * 256 + tid];
            cs[tid] = c0[b * 256 + tid];
            float hpart = __shfl_xor(h0v, 1, 64);
            if (!(tid & 1)) hp[tid >> 1] = pk2(h0v, hpart);
        }
        const float bh = bhh[r];
        const uint4* wp4 = (const uint4*)Wt2 + r;

        uint4 wreg[16];
        #pragma unroll
        for (int j = 0; j < 16; j++) wreg[j] = wp4[(size_t)(16 + j) * 1024];
        #pragma unroll
        for (int j = 0; j < 8; j++) {
            uint4 w = wp4[(size_t)(8 + j) * 1024];
            wlds[(j * 4 + 0) * 1024 + r] = w.x;
            wlds[(j * 4 + 1) * 1024 + r] = w.y;
            wlds[(j * 4 + 2) * 1024 + r] = w.z;
            wlds[(j * 4 + 3) * 1024 + r] = w.w;
        }
        __syncthreads();

        for (int t = 0; t < T_; t++) {
            float xp = xproj[((size_t)t * B_ + b) * 1024 + r];
            float acc = 0.0f;
            const uint4* hp4 = (const uint4*)hp;
            #pragma unroll
            for (int i = 0; i < 8; i++) {
                uint4 hv = hp4[i];
                uint4 w  = wp4[(size_t)i * 1024];
                acc = dot2f16(w.x, hv.x, acc);
                acc = dot2f16(w.y, hv.y, acc);
                acc = dot2f16(w.z, hv.z, acc);
                acc = dot2f16(w.w, hv.w, acc);
            }
            #pragma unroll
            for (int j = 0; j < 8; j++) {
                uint4 hv = hp4[8 + j];
                u32 w0 = wlds[(j * 4 + 0) * 1024 + r];
                u32 w1 = wlds[(j * 4 + 1) * 1024 + r];
                u32 w2 = wlds[(j * 4 + 2) * 1024 + r];
                u32 w3 = wlds[(j * 4 + 3) * 1024 + r];
                acc = dot2f16(w0, hv.x, acc);
                acc = dot2f16(w1, hv.y, acc);
                acc = dot2f16(w2, hv.z, acc);
                acc = dot2f16(w3, hv.w, acc);
            }
            #pragma unroll
            for (int j = 0; j < 16; j++) {
                uint4 hv = hp4[16 + j];
                acc = dot2f16(wreg[j].x, hv.x, acc);
                acc = dot2f16(wreg[j].y, hv.y, acc);
                acc = dot2f16(wreg[j].z, hv.z, acc);
                acc = dot2f16(wreg[j].w, hv.w, acc);
            }
            zs[r] = xp + bh + acc;
            __syncthreads();

            if (tid < 256) {
                float ig = fast_sigm(zs[tid]);
                float fg = fast_sigm(zs[256 + tid]);
                float gg = fast_tanh(zs[512 + tid]);
                float og = fast_sigm(zs[768 + tid]);
                float c = fg * cs[tid] + ig * gg;
                float h = og * fast_tanh(c);
                cs[tid] = c;
                hsave[(t << 8) + tid] = h;
                float hpart = __shfl_xor(h, 1, 64);
                if (!(tid & 1)) hp[tid >> 1] = pk2(h, hpart);
            }
            __syncthreads();
        }

        #pragma unroll
        for (int i = 0; i < 4; i++) {
            int idx = tid + i * 1024;
            int t = idx >> 8, h = idx & 255;
            combined[((size_t)t * B_ + b) * 512 + 256 + h] = hsave[idx];
        }
        if (tid < 256) {
            hT[b * 256 + tid] = hsave[(15 << 8) + tid];
            cT[b * 256 + tid] = cs[tid];
        }
    } else if (bid < 160) {
        float (*As2)[132] = (float (*)[132])smem;
        float (*Bs2)[132] = (float (*)[132])(smem + 4224);
        const int tile = bid - 32;
        const int bm = (tile >> 1) * 128;
        const int bn = (tile & 1) * 128;
        const int tx = tid & 31, ty = tid >> 5;
        const int lr = tid >> 3;
        const int lk = (tid & 7) * 4;

        const float* Ap = enc_raw + (size_t)(bm + lr) * 256;
        const float* Bp = We + (size_t)(bn + lr) * 256;
        float acc[4][4] = {};

        for (int k0 = 0; k0 < 256; k0 += 32) {
            float4 a4 = *(const float4*)(Ap + k0 + lk);
            float4 b4 = *(const float4*)(Bp + k0 + lk);
            As2[lk + 0][lr] = a4.x; As2[lk + 1][lr] = a4.y;
            As2[lk + 2][lr] = a4.z; As2[lk + 3][lr] = a4.w;
            Bs2[lk + 0][lr] = b4.x; Bs2[lk + 1][lr] = b4.y;
            Bs2[lk + 2][lr] = b4.z; Bs2[lk + 3][lr] = b4.w;
            __syncthreads();
            #pragma unroll
            for (int kk = 0; kk < 32; kk++) {
                float4 a = *(const float4*)&As2[kk][ty * 4];
                float4 b = *(const float4*)&Bs2[kk][tx * 4];
                acc[0][0] += a.x*b.x; acc[0][1] += a.x*b.y; acc[0][2] += a.x*b.z; acc[0][3] += a.x*b.w;
                acc[1][0] += a.y*b.x; acc[1][1] += a.y*b.y; acc[1][2] += a.y*b.z; acc[1][3] += a.y*b.w;
                acc[2][0] += a.z*b.x; acc[2][1] += a.z*b.y; acc[2][2] += a.z*b.z; acc[2][3] += a.z*b.w;
                acc[3][0] += a.w*b.x; acc[3][1] += a.w*b.y; acc[3][2] += a.w*b.z; acc[3][3] += a.w*b.w;
            }
            __syncthreads();
        }
        #pragma unroll
        for (int i = 0; i < 4; i++) {
            int m = bm + ty * 4 + i;
            #pragma unroll
            for (int j = 0; j < 4; j++) {
                int n = bn + tx * 4 + j;
                enct[(size_t)m * 256 + n] = acc[i][j] + be[n];
            }
        }
    } else if (bid < 176) {
        // Wd transpose: fp32 float4 [64][256] (dect stays full fp32)
        float (*tile)[65] = (float (*)[65])smem;
        const int w = tid >> 6;
        const int lane = tid & 63;
        int t = bid - 160;
        int h0 = (t >> 2) * 64, k0 = (t & 3) * 64;
        #pragma unroll
        for (int j = 0; j < 4; j++) {
            int row = w * 4 + j;
            tile[row][lane] = Wd[(size_t)(h0 + row) * 256 + k0 + lane];
        }
        __syncthreads();
        {
            int q = w;
            float4 v;
            v.x = tile[lane][4*q + 0];
            v.y = tile[lane][4*q + 1];
            v.z = tile[lane][4*q + 2];
            v.w = tile[lane][4*q + 3];
            ((float4*)Wdt)[(size_t)((k0 >> 2) + q) * 256 + h0 + lane] = v;
        }
    } else {
        // W_out -> WoT2 f16-pair transpose: uint4 [64 kq8][1000 v]
        float (*tile)[65] = (float (*)[65])smem;
        const int w = tid >> 6;        // 0..15
        const int lane = tid & 63;
        int t = bid - 176;             // 0..127
        int v0 = (t >> 3) * 64, k0 = (t & 7) * 64;
        #pragma unroll
        for (int j = 0; j < 4; j++) {
            int row = w * 4 + j;
            int v = v0 + row;
            tile[row][lane] = (v < V_) ? W_out[(size_t)v * 512 + k0 + lane] : 0.0f;
        }
        __syncthreads();
        if (w < 8) {
            int q = w;                 // kq8 within tile, 0..7
            int v = v0 + lane;
            if (v < V_) {
                uint4 val;
                val.x = pk2(tile[lane][8*q + 0], tile[lane][8*q + 1]);
                val.y = pk2(tile[lane][8*q + 2], tile[lane][8*q + 3]);
                val.z = pk2(tile[lane][8*q + 4], tile[lane][8*q + 5]);
                val.w = pk2(tile[lane][8*q + 6], tile[lane][8*q + 7]);
                ((uint4*)WoT2)[(size_t)((k0 >> 3) + q) * 1000 + v] = val;
            }
        }
    }
}

// ---------------------------------------------------------------------------
// Kernel 3: FUSED tail — round-2 structure (512 thr, grid 512, proven
// 57.8 us) with ONE round-8 change: the vocab-logits loop uses f16-pair
// fdot2 (WoT2) instead of bf16 blo/bhi. crow is pre-packed to 256 f16-pair
// words after ctx. 64 iters x (2 uint4 loads + 1 LDS uint4 + 8 fdot2) vs
// 128 x (1 load + 8 unpack + 8 FMA): ~60% fewer VALU instr in the dominant
// phase. f16 weights (10-bit mantissa) replace bf16 (7-bit) -> weight error
// shrinks; ctx/h pay 2^-11 rounding. All other phases byte-identical.
// ---------------------------------------------------------------------------
__global__ __launch_bounds__(512)
void attn_logits(const float* __restrict__ enct,        // [S,B,H]
                 const float* __restrict__ combined_in, // [T,B,512] (2nd half)
                 const float* __restrict__ Wdt,         // float4 [64][256]
                 const float* __restrict__ bd,
                 const float* __restrict__ enc_raw,     // [S,B,H]
                 const float* __restrict__ wa, const float* __restrict__ ba,
                 const int* __restrict__ lens,
                 const u32* __restrict__ WoT2,          // uint4 [64][1000] f16-pair
                 const float* __restrict__ b_out,       // [1000]
                 float* __restrict__ ctx_out,           // [B,T,H] (d_out)
                 float* __restrict__ probs)             // [T,B,V] (d_out)
{
    const int bid = blockIdx.x;
    const int b = bid & 31;          // XCD swizzle
    const int t = bid >> 5;
    const int tid = threadIdx.x;
    const int wv = tid >> 6, lane = tid & 63;
    __shared__ float ds[256], was[256], sc[256];
    __shared__ float crow[512];
    __shared__ float tmp2[512];
    __shared__ float lrow[1000];
    __shared__ float red[8], red2[8];
    __shared__ u32 crow_pk[256];

    if (tid < 256) {
        crow[256 + tid] = combined_in[((size_t)t * B_ + b) * 512 + 256 + tid];
        was[tid] = wa[tid];
    }
    const int len = lens[b];
    const float bav = ba[0];
    __syncthreads();

    {
        const int h   = tid & 255;
        const int kq0 = (tid >> 8) * 32;
        float acc = 0.0f;
        const float4* wp = (const float4*)Wdt + h;
        #pragma unroll 8
        for (int kq = kq0; kq < kq0 + 32; kq++) {
            float4 w = wp[(size_t)kq * 256];
            float4 c = *(const float4*)&crow[256 + kq * 4];
            acc += w.x * c.x;
            acc += w.y * c.y;
            acc += w.z * c.z;
            acc += w.w * c.w;
        }
        tmp2[tid] = acc;
    }
    __syncthreads();
    if (tid < 256) ds[tid] = bd[tid] + tmp2[tid] + tmp2[tid + 256];
    __syncthreads();

    for (int s = wv; s < len; s += 8) {
        const float* er = enct + ((size_t)s * B_ + b) * 256;
        float sum = 0.0f;
        #pragma unroll
        for (int j = 0; j < 4; j++) {
            int h = lane + 64 * j;
            sum += fast_tanh(er[h] + ds[h]) * was[h];
        }
        #pragma unroll
        for (int off = 32; off >= 1; off >>= 1) sum += __shfl_xor(sum, off, 64);
        if (lane == 0) sc[s] = sum + bav;
    }
    __syncthreads();

    float x = (tid < len) ? sc[tid] : -INFINITY;
    float m = x;
    #pragma unroll
    for (int off = 32; off >= 1; off >>= 1) m = fmaxf(m, __shfl_xor(m, off, 64));
    if (lane == 0) red[wv] = m;
    __syncthreads();
    m = red[0];
    #pragma unroll
    for (int i = 1; i < 8; i++) m = fmaxf(m, red[i]);
    float e = __expf(x - m);
    float ssum = e;
    #pragma unroll
    for (int off = 32; off >= 1; off >>= 1) ssum += __shfl_xor(ssum, off, 64);
    if (lane == 0) red2[wv] = ssum;
    __syncthreads();
    ssum = red2[0] + red2[1] + red2[2] + red2[3] + red2[4] + red2[5] + red2[6] + red2[7];
    if (tid < 256) sc[tid] = e / ssum;
    __syncthreads();

    {
        const int h  = tid & 255;
        const int sg = tid >> 8;
        const int mid = (len + 1) >> 1;
        const int s0 = sg ? mid : 0;
        const int s1 = sg ? len : mid;
        float cacc = 0.0f;
        const float* eb = enc_raw + (size_t)b * 256 + h;
        #pragma unroll 4
        for (int s = s0; s < s1; s++) cacc += sc[s] * eb[(size_t)s * (B_ * H_)];
        tmp2[tid] = cacc;
    }
    __syncthreads();
    if (tid < 256) {
        float ctx = tmp2[tid] + tmp2[tid + 256];
        ctx_out[((size_t)b * T_ + t) * 256 + tid] = ctx;
        crow[tid] = ctx;
    }
    __syncthreads();
    // pack crow (ctx | h) into 256 f16-pair words for fdot2
    if (tid < 256) crow_pk[tid] = pk2(crow[2 * tid], crow[2 * tid + 1]);
    __syncthreads();

    if (tid < 500) {
        const int v0 = tid * 2;
        float a0 = b_out[v0], a1 = b_out[v0 + 1];
        const uint4* wp = (const uint4*)WoT2 + v0;
        const uint4* hp4 = (const uint4*)crow_pk;
        #pragma unroll 4
        for (int kq = 0; kq < 64; kq++) {
            uint4 w0 = wp[(size_t)kq * 1000];
            uint4 w1 = wp[(size_t)kq * 1000 + 1];
            uint4 hv = hp4[kq];
            a0 = dot2f16(w0.x, hv.x, a0);
            a0 = dot2f16(w0.y, hv.y, a0);
            a0 = dot2f16(w0.z, hv.z, a0);
            a0 = dot2f16(w0.w, hv.w, a0);
            a1 = dot2f16(w1.x, hv.x, a1);
            a1 = dot2f16(w1.y, hv.y, a1);
            a1 = dot2f16(w1.z, hv.z, a1);
            a1 = dot2f16(w1.w, hv.w, a1);
        }
        lrow[v0] = a0;
        lrow[v0 + 1] = a1;
    }
    __syncthreads();

    float v0v = -INFINITY, v1v = -INFINITY;
    if (tid < 500) { v0v = lrow[tid * 2]; v1v = lrow[tid * 2 + 1]; }
    float mx = fmaxf(v0v, v1v);
    #pragma unroll
    for (int off = 32; off >= 1; off >>= 1) mx = fmaxf(mx, __shfl_xor(mx, off, 64));
    if (lane == 0) red[wv] = mx;
    __syncthreads();
    mx = red[0];
    #pragma unroll
    for (int i = 1; i < 8; i++) mx = fmaxf(mx, red[i]);
    float e0 = __expf(v0v - mx), e1 = __expf(v1v - mx);
    float s2 = e0 + e1;
    #pragma unroll
    for (int off = 32; off >= 1; off >>= 1) s2 += __shfl_xor(s2, off, 64);
    if (lane == 0) red2[wv] = s2;
    __syncthreads();
    s2 = red2[0] + red2[1] + red2[2] + red2[3] + red2[4] + red2[5] + red2[6] + red2[7];
    float inv = 1.0f / s2;
    if (tid < 500) {
        float2 pv = make_float2(e0 * inv, e1 * inv);
        *(float2*)&probs[((size_t)t * B_ + b) * V_ + tid * 2] = pv;
    }
}

extern "C" void kernel_launch(void* const* d_in, const int* in_sizes, int n_in,
                              void* d_out, int out_size, void* d_ws, size_t ws_size,
                              hipStream_t stream) {
    const int*   tv       = (const int*)d_in[0];
    const float* h0       = (const float*)d_in[1];
    const float* c0       = (const float*)d_in[2];
    const float* enc_raw  = (const float*)d_in[3];
    const int*   lens     = (const int*)d_in[4];
    const float* emb      = (const float*)d_in[5];
    const float* W_ih     = (const float*)d_in[6];
    const float* W_hh     = (const float*)d_in[7];
    const float* b_ih     = (const float*)d_in[8];
    const float* b_hh     = (const float*)d_in[9];
    const float* We       = (const float*)d_in[10];
    const float* be       = (const float*)d_in[11];
    const float* Wd       = (const float*)d_in[12];
    const float* bd       = (const float*)d_in[13];
    const float* wa       = (const float*)d_in[14];
    const float* ba       = (const float*)d_in[15];
    const float* W_out    = (const float*)d_in[16];
    const float* b_out    = (const float*)d_in[17];

    // workspace layout (fp32 words)
    float* ws       = (float*)d_ws;
    float* enct     = ws;                       // [8192,256]  2,097,152
    float* xproj    = ws + 2097152;             // [512,1024]    524,288
    float* Wdt      = ws + 2621440;             // float4 [64][256]  65,536 f
    u32*   WoT2     = (u32*)(ws + 2752512);     // uint4 [64][1000] f16-pair, 1 MB
    float* combined = ws + 3264512;             // [512,512]     262,144
    u32*   Wt2      = (u32*)(ws + 3526656);     // uint4 [32][1024]  512 KB

    // d_out layout (fp32): probs [T,B,V], hT, cT, ctx [B,T,H]
    float* out      = (float*)d_out;
    float* probs    = out;
    float* hT       = out + 512000;
    float* cT       = out + 520192;
    float* ctx_out  = out + 528384;

    // 1) xproj GEMM (32x64 tiles) + Whh->Wt2 transpose
    prep_xproj<<<320, 256, 0, stream>>>(emb, tv, W_ih, b_ih, xproj, W_hh, Wt2);
    // 2) LSTM + enc_t + Wd/WoT2 transposes
    lstm_enct<<<304, 1024, 0, stream>>>(xproj, Wt2, b_hh, h0, c0, combined, hT, cT,
                                        enc_raw, We, be, enct,
                                        Wd, Wdt, W_out, WoT2);
    // 3) fused attention + logits (f16 fdot2 vocab) + vocab softmax
    attn_logits<<<512, 512, 0, stream>>>(enct, combined, Wdt, bd, enc_raw,
                                         wa, ba, lens, WoT2, b_out, ctx_out, probs);
}

// Round 9
// 208.844 us; speedup vs baseline: 1.0038x; 1.0038x over previous
//
#include <hip/hip_runtime.h>
#include <hip/hip_fp16.h>
#include <math.h>

typedef unsigned int u32;
typedef unsigned short u16;

#define T_ 16
#define B_ 32
#define S_ 256
#define H_ 256
#define E_ 300
#define V_ 1000

typedef _Float16 h2_t __attribute__((ext_vector_type(2)));
typedef __fp16  fp16v2 __attribute__((ext_vector_type(2)));

__device__ __forceinline__ float fast_tanh(float x) {
    return 1.0f - 2.0f / (__expf(2.0f * x) + 1.0f);
}
__device__ __forceinline__ float fast_sigm(float x) {
    return 1.0f / (1.0f + __expf(-x));
}
__device__ __forceinline__ u32 pk2(float a, float b) {
    union { fp16v2 v; u32 u; } c; c.v = __builtin_amdgcn_cvt_pkrtz(a, b); return c.u;
}
__device__ __forceinline__ h2_t u2h2(u32 u) {
    union { u32 a; h2_t b; } c; c.a = u; return c.b;
}
__device__ __forceinline__ float dot2f16(u32 w, u32 h, float acc) {
#if __has_builtin(__builtin_amdgcn_fdot2)
    return __builtin_amdgcn_fdot2(u2h2(w), u2h2(h), acc, false);
#else
    h2_t wv = u2h2(w), hv = u2h2(h);
    return acc + (float)wv.x * (float)hv.x + (float)wv.y * (float)hv.y;
#endif
}

// ---------------------------------------------------------------------------
// Kernel 1: prep v6 (round-7 proven) — xproj GEMM 32x64 tiles + Whh->Wt2.
// ---------------------------------------------------------------------------
__global__ __launch_bounds__(256)
void prep_xproj(const float* __restrict__ emb, const int* __restrict__ tv,
                const float* __restrict__ W_ih, const float* __restrict__ b_ih,
                float* __restrict__ xproj,
                const float* __restrict__ Whh,  u32* __restrict__ Wt2)
{
    const int bid = blockIdx.x;
    const int tid = threadIdx.x;
    if (bid < 256) {
        __shared__ float As[32][33];
        __shared__ float Bs[32][64];
        const int bm = (bid >> 4) * 32;
        const int bn = (bid & 15) * 64;
        const int ty = tid >> 4;
        const int tx = tid & 15;
        const int alr = tid >> 3;
        const int alk = (tid & 7) * 4;
        const int blr = tid >> 2;
        const int blk = (tid & 3) * 8;

        const float* Ap = emb + (size_t)tv[bm + alr] * E_;
        const float* Bp = W_ih + (size_t)(bn + blr) * E_;

        float acc[2][4] = {};
        for (int k0 = 0; k0 < E_; k0 += 32) {
            int kb = k0 + alk;
            float4 a4;
            if (kb + 4 <= E_) {
                a4 = *(const float4*)(Ap + kb);
            } else {
                a4.x = (kb + 0 < E_) ? Ap[kb + 0] : 0.0f;
                a4.y = (kb + 1 < E_) ? Ap[kb + 1] : 0.0f;
                a4.z = (kb + 2 < E_) ? Ap[kb + 2] : 0.0f;
                a4.w = (kb + 3 < E_) ? Ap[kb + 3] : 0.0f;
            }
            As[alk + 0][alr] = a4.x; As[alk + 1][alr] = a4.y;
            As[alk + 2][alr] = a4.z; As[alk + 3][alr] = a4.w;

            int kbb = k0 + blk;
            float bv[8];
            if (kbb + 8 <= E_) {
                float4 p0 = *(const float4*)(Bp + kbb);
                float4 p1 = *(const float4*)(Bp + kbb + 4);
                bv[0]=p0.x; bv[1]=p0.y; bv[2]=p0.z; bv[3]=p0.w;
                bv[4]=p1.x; bv[5]=p1.y; bv[6]=p1.z; bv[7]=p1.w;
            } else {
                #pragma unroll
                for (int j = 0; j < 8; j++) bv[j] = (kbb + j < E_) ? Bp[kbb + j] : 0.0f;
            }
            #pragma unroll
            for (int j = 0; j < 8; j++) Bs[blk + j][blr] = bv[j];
            __syncthreads();
            #pragma unroll
            for (int kk = 0; kk < 32; kk++) {
                float ax = As[kk][ty * 2], ay = As[kk][ty * 2 + 1];
                float4 b = *(const float4*)&Bs[kk][tx * 4];
                acc[0][0] += ax*b.x; acc[0][1] += ax*b.y; acc[0][2] += ax*b.z; acc[0][3] += ax*b.w;
                acc[1][0] += ay*b.x; acc[1][1] += ay*b.y; acc[1][2] += ay*b.z; acc[1][3] += ay*b.w;
            }
            __syncthreads();
        }
        #pragma unroll
        for (int i = 0; i < 2; i++) {
            int m = bm + ty * 2 + i;
            #pragma unroll
            for (int j = 0; j < 4; j++) {
                int n = bn + tx * 4 + j;
                xproj[(size_t)m * 1024 + n] = acc[i][j] + b_ih[n];
            }
        }
        return;
    }
    // Whh transpose -> Wt2 uint4 [32][1024] (f16 pairs), bids 256..319
    __shared__ float tile[64][65];
    const int wv = tid >> 6;
    const int lane = tid & 63;
    int t = bid - 256;
    int r0 = (t >> 2) * 64, k0 = (t & 3) * 64;
    #pragma unroll 4
    for (int j = 0; j < 16; j++) {
        int row = wv * 16 + j;
        tile[row][lane] = Whh[(size_t)(r0 + row) * 256 + k0 + lane];
    }
    __syncthreads();
    #pragma unroll
    for (int it = 0; it < 2; it++) {
        int q = wv + 4 * it;
        uint4 val;
        val.x = pk2(tile[lane][8*q + 0], tile[lane][8*q + 1]);
        val.y = pk2(tile[lane][8*q + 2], tile[lane][8*q + 3]);
        val.z = pk2(tile[lane][8*q + 4], tile[lane][8*q + 5]);
        val.w = pk2(tile[lane][8*q + 6], tile[lane][8*q + 7]);
        ((uint4*)Wt2)[(size_t)((k0 >> 3) + q) * 1024 + r0 + lane] = val;
    }
}

// ---------------------------------------------------------------------------
// Kernel 2: lstm + enc_t + transposes. Round-9 change: with the 4,4 pin
// proven working (r7), shift 4 more groups from L2-stream into registers:
// wreg[20] (80 VGPR, demand ~110 < 128 budget -> no spill), 8 LDS groups
// (4..11), only 4 streamed (0..3). r5 measured ~0.6 us per streamed group.
// Accumulation order 0..31 ascending preserved -> bit-identical.
//   bid 32..159 : enc_t 128x128 tile
//   bid 160..175: Wd transpose (fp32)
//   bid 176..303: W_out -> WoT2 f16-pair transpose
// ---------------------------------------------------------------------------
__global__ __launch_bounds__(1024)
__attribute__((amdgpu_waves_per_eu(4, 4)))
void lstm_enct(const float* __restrict__ xproj,   // [T,B,1024]
               const u32*   __restrict__ Wt2,     // uint4 [32][1024]
               const float* __restrict__ bhh,     // [1024]
               const float* __restrict__ h0, const float* __restrict__ c0,
               float* __restrict__ combined,      // [T,B,512] second half
               float* __restrict__ hT, float* __restrict__ cT,
               const float* __restrict__ enc_raw, // [8192,256]
               const float* __restrict__ We,      // [256,256]
               const float* __restrict__ be,
               float* __restrict__ enct,          // [8192,256]
               const float* __restrict__ Wd,   float* __restrict__ Wdt,
               const float* __restrict__ W_out, u32* __restrict__ WoT2)
{
    const int bid = blockIdx.x;
    const int tid = threadIdx.x;
    __shared__ __align__(16) u32 smem[38272];

    if (bid < 32) {
        float* zs = (float*)smem;            // [1024]
        float* cs = (float*)(smem + 1024);   // [256]
        u32*   hp = smem + 1280;             // [128]
        u32*   wlds = smem + 1408;           // [32][1024] dword-sliced (8 groups)
        float* hsave = (float*)(smem + 34176); // [16][256]
        const int b = bid;
        const int r = tid;
        if (tid < 256) {
            float h0v = h0[b * 256 + tid];
            cs[tid] = c0[b * 256 + tid];
            float hpart = __shfl_xor(h0v, 1, 64);
            if (!(tid & 1)) hp[tid >> 1] = pk2(h0v, hpart);
        }
        const float bh = bhh[r];
        const uint4* wp4 = (const uint4*)Wt2 + r;

        // groups 12..31 -> registers (80 VGPR)
        uint4 wreg[20];
        #pragma unroll
        for (int j = 0; j < 20; j++) wreg[j] = wp4[(size_t)(12 + j) * 1024];
        // groups 4..11 -> LDS ([dw][r]: lane stride 4B, no conflict)
        #pragma unroll
        for (int j = 0; j < 8; j++) {
            uint4 w = wp4[(size_t)(4 + j) * 1024];
            wlds[(j * 4 + 0) * 1024 + r] = w.x;
            wlds[(j * 4 + 1) * 1024 + r] = w.y;
            wlds[(j * 4 + 2) * 1024 + r] = w.z;
            wlds[(j * 4 + 3) * 1024 + r] = w.w;
        }
        __syncthreads();

        for (int t = 0; t < T_; t++) {
            float xp = xproj[((size_t)t * B_ + b) * 1024 + r];
            float acc = 0.0f;
            const uint4* hp4 = (const uint4*)hp;
            // groups 0..3: streamed from L2 (64 KB/step)
            #pragma unroll
            for (int i = 0; i < 4; i++) {
                uint4 hv = hp4[i];
                uint4 w  = wp4[(size_t)i * 1024];
                acc = dot2f16(w.x, hv.x, acc);
                acc = dot2f16(w.y, hv.y, acc);
                acc = dot2f16(w.z, hv.z, acc);
                acc = dot2f16(w.w, hv.w, acc);
            }
            // groups 4..11: LDS-resident
            #pragma unroll
            for (int j = 0; j < 8; j++) {
                uint4 hv = hp4[4 + j];
                u32 w0 = wlds[(j * 4 + 0) * 1024 + r];
                u32 w1 = wlds[(j * 4 + 1) * 1024 + r];
                u32 w2 = wlds[(j * 4 + 2) * 1024 + r];
                u32 w3 = wlds[(j * 4 + 3) * 1024 + r];
                acc = dot2f16(w0, hv.x, acc);
                acc = dot2f16(w1, hv.y, acc);
                acc = dot2f16(w2, hv.z, acc);
                acc = dot2f16(w3, hv.w, acc);
            }
            // groups 12..31: register-resident
            #pragma unroll
            for (int j = 0; j < 20; j++) {
                uint4 hv = hp4[12 + j];
                acc = dot2f16(wreg[j].x, hv.x, acc);
                acc = dot2f16(wreg[j].y, hv.y, acc);
                acc = dot2f16(wreg[j].z, hv.z, acc);
                acc = dot2f16(wreg[j].w, hv.w, acc);
            }
            zs[r] = xp + bh + acc;
            __syncthreads();

            if (tid < 256) {
                float ig = fast_sigm(zs[tid]);
                float fg = fast_sigm(zs[256 + tid]);
                float gg = fast_tanh(zs[512 + tid]);
                float og = fast_sigm(zs[768 + tid]);
                float c = fg * cs[tid] + ig * gg;
                float h = og * fast_tanh(c);
                cs[tid] = c;
                hsave[(t << 8) + tid] = h;
                float hpart = __shfl_xor(h, 1, 64);
                if (!(tid & 1)) hp[tid >> 1] = pk2(h, hpart);
            }
            __syncthreads();
        }

        #pragma unroll
        for (int i = 0; i < 4; i++) {
            int idx = tid + i * 1024;
            int t = idx >> 8, h = idx & 255;
            combined[((size_t)t * B_ + b) * 512 + 256 + h] = hsave[idx];
        }
        if (tid < 256) {
            hT[b * 256 + tid] = hsave[(15 << 8) + tid];
            cT[b * 256 + tid] = cs[tid];
        }
    } else if (bid < 160) {
        float (*As2)[132] = (float (*)[132])smem;
        float (*Bs2)[132] = (float (*)[132])(smem + 4224);
        const int tile = bid - 32;
        const int bm = (tile >> 1) * 128;
        const int bn = (tile & 1) * 128;
        const int tx = tid & 31, ty = tid >> 5;
        const int lr = tid >> 3;
        const int lk = (tid & 7) * 4;

        const float* Ap = enc_raw + (size_t)(bm + lr) * 256;
        const float* Bp = We + (size_t)(bn + lr) * 256;
        float acc[4][4] = {};

        for (int k0 = 0; k0 < 256; k0 += 32) {
            float4 a4 = *(const float4*)(Ap + k0 + lk);
            float4 b4 = *(const float4*)(Bp + k0 + lk);
            As2[lk + 0][lr] = a4.x; As2[lk + 1][lr] = a4.y;
            As2[lk + 2][lr] = a4.z; As2[lk + 3][lr] = a4.w;
            Bs2[lk + 0][lr] = b4.x; Bs2[lk + 1][lr] = b4.y;
            Bs2[lk + 2][lr] = b4.z; Bs2[lk + 3][lr] = b4.w;
            __syncthreads();
            #pragma unroll
            for (int kk = 0; kk < 32; kk++) {
                float4 a = *(const float4*)&As2[kk][ty * 4];
                float4 b = *(const float4*)&Bs2[kk][tx * 4];
                acc[0][0] += a.x*b.x; acc[0][1] += a.x*b.y; acc[0][2] += a.x*b.z; acc[0][3] += a.x*b.w;
                acc[1][0] += a.y*b.x; acc[1][1] += a.y*b.y; acc[1][2] += a.y*b.z; acc[1][3] += a.y*b.w;
                acc[2][0] += a.z*b.x; acc[2][1] += a.z*b.y; acc[2][2] += a.z*b.z; acc[2][3] += a.z*b.w;
                acc[3][0] += a.w*b.x; acc[3][1] += a.w*b.y; acc[3][2] += a.w*b.z; acc[3][3] += a.w*b.w;
            }
            __syncthreads();
        }
        #pragma unroll
        for (int i = 0; i < 4; i++) {
            int m = bm + ty * 4 + i;
            #pragma unroll
            for (int j = 0; j < 4; j++) {
                int n = bn + tx * 4 + j;
                enct[(size_t)m * 256 + n] = acc[i][j] + be[n];
            }
        }
    } else if (bid < 176) {
        // Wd transpose: fp32 float4 [64][256]
        float (*tile)[65] = (float (*)[65])smem;
        const int w = tid >> 6;
        const int lane = tid & 63;
        int t = bid - 160;
        int h0 = (t >> 2) * 64, k0 = (t & 3) * 64;
        #pragma unroll
        for (int j = 0; j < 4; j++) {
            int row = w * 4 + j;
            tile[row][lane] = Wd[(size_t)(h0 + row) * 256 + k0 + lane];
        }
        __syncthreads();
        {
            int q = w;
            float4 v;
            v.x = tile[lane][4*q + 0];
            v.y = tile[lane][4*q + 1];
            v.z = tile[lane][4*q + 2];
            v.w = tile[lane][4*q + 3];
            ((float4*)Wdt)[(size_t)((k0 >> 2) + q) * 256 + h0 + lane] = v;
        }
    } else {
        // W_out -> WoT2 f16-pair transpose: uint4 [64 kq8][1000 v]
        float (*tile)[65] = (float (*)[65])smem;
        const int w = tid >> 6;        // 0..15
        const int lane = tid & 63;
        int t = bid - 176;             // 0..127
        int v0 = (t >> 3) * 64, k0 = (t & 7) * 64;
        #pragma unroll
        for (int j = 0; j < 4; j++) {
            int row = w * 4 + j;
            int v = v0 + row;
            tile[row][lane] = (v < V_) ? W_out[(size_t)v * 512 + k0 + lane] : 0.0f;
        }
        __syncthreads();
        if (w < 8) {
            int q = w;                 // kq8 within tile, 0..7
            int v = v0 + lane;
            if (v < V_) {
                uint4 val;
                val.x = pk2(tile[lane][8*q + 0], tile[lane][8*q + 1]);
                val.y = pk2(tile[lane][8*q + 2], tile[lane][8*q + 3]);
                val.z = pk2(tile[lane][8*q + 4], tile[lane][8*q + 5]);
                val.w = pk2(tile[lane][8*q + 6], tile[lane][8*q + 7]);
                ((uint4*)WoT2)[(size_t)((k0 >> 3) + q) * 1000 + v] = val;
            }
        }
    }
}

// ---------------------------------------------------------------------------
// Kernel 3: FUSED tail — round-8 post-mortem: VALUBusy 46->33% with dur
// UNCHANGED proves attn is memory-LATENCY bound, not VALU bound. Round-9:
// raise memory-level parallelism only; every accumulation order unchanged:
//   scores: software-pipelined (issue row s+8 loads before reducing row s)
//   ctx:    unroll 4 -> 8 (8 loads in flight)
//   vocab:  unroll 4 -> 8
// ---------------------------------------------------------------------------
__global__ __launch_bounds__(512)
void attn_logits(const float* __restrict__ enct,        // [S,B,H]
                 const float* __restrict__ combined_in, // [T,B,512] (2nd half)
                 const float* __restrict__ Wdt,         // float4 [64][256]
                 const float* __restrict__ bd,
                 const float* __restrict__ enc_raw,     // [S,B,H]
                 const float* __restrict__ wa, const float* __restrict__ ba,
                 const int* __restrict__ lens,
                 const u32* __restrict__ WoT2,          // uint4 [64][1000] f16-pair
                 const float* __restrict__ b_out,       // [1000]
                 float* __restrict__ ctx_out,           // [B,T,H] (d_out)
                 float* __restrict__ probs)             // [T,B,V] (d_out)
{
    const int bid = blockIdx.x;
    const int b = bid & 31;          // XCD swizzle
    const int t = bid >> 5;
    const int tid = threadIdx.x;
    const int wv = tid >> 6, lane = tid & 63;
    __shared__ float ds[256], was[256], sc[256];
    __shared__ float crow[512];
    __shared__ float tmp2[512];
    __shared__ float lrow[1000];
    __shared__ float red[8], red2[8];
    __shared__ u32 crow_pk[256];

    if (tid < 256) {
        crow[256 + tid] = combined_in[((size_t)t * B_ + b) * 512 + 256 + tid];
        was[tid] = wa[tid];
    }
    const int len = lens[b];
    const float bav = ba[0];
    __syncthreads();

    {
        const int h   = tid & 255;
        const int kq0 = (tid >> 8) * 32;
        float acc = 0.0f;
        const float4* wp = (const float4*)Wdt + h;
        #pragma unroll 8
        for (int kq = kq0; kq < kq0 + 32; kq++) {
            float4 w = wp[(size_t)kq * 256];
            float4 c = *(const float4*)&crow[256 + kq * 4];
            acc += w.x * c.x;
            acc += w.y * c.y;
            acc += w.z * c.z;
            acc += w.w * c.w;
        }
        tmp2[tid] = acc;
    }
    __syncthreads();
    if (tid < 256) ds[tid] = bd[tid] + tmp2[tid] + tmp2[tid + 256];
    __syncthreads();

    // scores: software-pipelined row loads (issue s+8 before reducing s).
    // Per-s sum order identical to round 2 -> bit-identical.
    {
        float c0 = 0.f, c1 = 0.f, c2 = 0.f, c3 = 0.f;
        if (wv < len) {
            const float* er = enct + ((size_t)wv * B_ + b) * 256;
            c0 = er[lane]; c1 = er[lane + 64]; c2 = er[lane + 128]; c3 = er[lane + 192];
        }
        for (int s = wv; s < len; s += 8) {
            int sn = s + 8;
            float n0 = 0.f, n1 = 0.f, n2 = 0.f, n3 = 0.f;
            if (sn < len) {
                const float* ern = enct + ((size_t)sn * B_ + b) * 256;
                n0 = ern[lane]; n1 = ern[lane + 64]; n2 = ern[lane + 128]; n3 = ern[lane + 192];
            }
            float sum = 0.0f;
            sum += fast_tanh(c0 + ds[lane]) * was[lane];
            sum += fast_tanh(c1 + ds[lane + 64]) * was[lane + 64];
            sum += fast_tanh(c2 + ds[lane + 128]) * was[lane + 128];
            sum += fast_tanh(c3 + ds[lane + 192]) * was[lane + 192];
            #pragma unroll
            for (int off = 32; off >= 1; off >>= 1) sum += __shfl_xor(sum, off, 64);
            if (lane == 0) sc[s] = sum + bav;
            c0 = n0; c1 = n1; c2 = n2; c3 = n3;
        }
    }
    __syncthreads();

    float x = (tid < len) ? sc[tid] : -INFINITY;
    float m = x;
    #pragma unroll
    for (int off = 32; off >= 1; off >>= 1) m = fmaxf(m, __shfl_xor(m, off, 64));
    if (lane == 0) red[wv] = m;
    __syncthreads();
    m = red[0];
    #pragma unroll
    for (int i = 1; i < 8; i++) m = fmaxf(m, red[i]);
    float e = __expf(x - m);
    float ssum = e;
    #pragma unroll
    for (int off = 32; off >= 1; off >>= 1) ssum += __shfl_xor(ssum, off, 64);
    if (lane == 0) red2[wv] = ssum;
    __syncthreads();
    ssum = red2[0] + red2[1] + red2[2] + red2[3] + red2[4] + red2[5] + red2[6] + red2[7];
    if (tid < 256) sc[tid] = e / ssum;
    __syncthreads();

    {
        const int h  = tid & 255;
        const int sg = tid >> 8;
        const int mid = (len + 1) >> 1;
        const int s0 = sg ? mid : 0;
        const int s1 = sg ? len : mid;
        float cacc = 0.0f;
        const float* eb = enc_raw + (size_t)b * 256 + h;
        #pragma unroll 8
        for (int s = s0; s < s1; s++) cacc += sc[s] * eb[(size_t)s * (B_ * H_)];
        tmp2[tid] = cacc;
    }
    __syncthreads();
    if (tid < 256) {
        float ctx = tmp2[tid] + tmp2[tid + 256];
        ctx_out[((size_t)b * T_ + t) * 256 + tid] = ctx;
        crow[tid] = ctx;
    }
    __syncthreads();
    if (tid < 256) crow_pk[tid] = pk2(crow[2 * tid], crow[2 * tid + 1]);
    __syncthreads();

    if (tid < 500) {
        const int v0 = tid * 2;
        float a0 = b_out[v0], a1 = b_out[v0 + 1];
        const uint4* wp = (const uint4*)WoT2 + v0;
        const uint4* hp4 = (const uint4*)crow_pk;
        #pragma unroll 8
        for (int kq = 0; kq < 64; kq++) {
            uint4 w0 = wp[(size_t)kq * 1000];
            uint4 w1 = wp[(size_t)kq * 1000 + 1];
            uint4 hv = hp4[kq];
            a0 = dot2f16(w0.x, hv.x, a0);
            a0 = dot2f16(w0.y, hv.y, a0);
            a0 = dot2f16(w0.z, hv.z, a0);
            a0 = dot2f16(w0.w, hv.w, a0);
            a1 = dot2f16(w1.x, hv.x, a1);
            a1 = dot2f16(w1.y, hv.y, a1);
            a1 = dot2f16(w1.z, hv.z, a1);
            a1 = dot2f16(w1.w, hv.w, a1);
        }
        lrow[v0] = a0;
        lrow[v0 + 1] = a1;
    }
    __syncthreads();

    float v0v = -INFINITY, v1v = -INFINITY;
    if (tid < 500) { v0v = lrow[tid * 2]; v1v = lrow[tid * 2 + 1]; }
    float mx = fmaxf(v0v, v1v);
    #pragma unroll
    for (int off = 32; off >= 1; off >>= 1) mx = fmaxf(mx, __shfl_xor(mx, off, 64));
    if (lane == 0) red[wv] = mx;
    __syncthreads();
    mx = red[0];
    #pragma unroll
    for (int i = 1; i < 8; i++) mx = fmaxf(mx, red[i]);
    float e0 = __expf(v0v - mx), e1 = __expf(v1v - mx);
    float s2 = e0 + e1;
    #pragma unroll
    for (int off = 32; off >= 1; off >>= 1) s2 += __shfl_xor(s2, off, 64);
    if (lane == 0) red2[wv] = s2;
    __syncthreads();
    s2 = red2[0] + red2[1] + red2[2] + red2[3] + red2[4] + red2[5] + red2[6] + red2[7];
    float inv = 1.0f / s2;
    if (tid < 500) {
        float2 pv = make_float2(e0 * inv, e1 * inv);
        *(float2*)&probs[((size_t)t * B_ + b) * V_ + tid * 2] = pv;
    }
}

extern "C" void kernel_launch(void* const* d_in, const int* in_sizes, int n_in,
                              void* d_out, int out_size, void* d_ws, size_t ws_size,
                              hipStream_t stream) {
    const int*   tv       = (const int*)d_in[0];
    const float* h0       = (const float*)d_in[1];
    const float* c0       = (const float*)d_in[2];
    const float* enc_raw  = (const float*)d_in[3];
    const int*   lens     = (const int*)d_in[4];
    const float* emb      = (const float*)d_in[5];
    const float* W_ih     = (const float*)d_in[6];
    const float* W_hh     = (const float*)d_in[7];
    const float* b_ih     = (const float*)d_in[8];
    const float* b_hh     = (const float*)d_in[9];
    const float* We       = (const float*)d_in[10];
    const float* be       = (const float*)d_in[11];
    const float* Wd       = (const float*)d_in[12];
    const float* bd       = (const float*)d_in[13];
    const float* wa       = (const float*)d_in[14];
    const float* ba       = (const float*)d_in[15];
    const float* W_out    = (const float*)d_in[16];
    const float* b_out    = (const float*)d_in[17];

    // workspace layout (fp32 words)
    float* ws       = (float*)d_ws;
    float* enct     = ws;                       // [8192,256]  2,097,152
    float* xproj    = ws + 2097152;             // [512,1024]    524,288
    float* Wdt      = ws + 2621440;             // float4 [64][256]  65,536 f
    u32*   WoT2     = (u32*)(ws + 2752512);     // uint4 [64][1000] f16-pair, 1 MB
    float* combined = ws + 3264512;             // [512,512]     262,144
    u32*   Wt2      = (u32*)(ws + 3526656);     // uint4 [32][1024]  512 KB

    // d_out layout (fp32): probs [T,B,V], hT, cT, ctx [B,T,H]
    float* out      = (float*)d_out;
    float* probs    = out;
    float* hT       = out + 512000;
    float* cT       = out + 520192;
    float* ctx_out  = out + 528384;

    // 1) xproj GEMM (32x64 tiles) + Whh->Wt2 transpose
    prep_xproj<<<320, 256, 0, stream>>>(emb, tv, W_ih, b_ih, xproj, W_hh, Wt2);
    // 2) LSTM (20 reg + 8 LDS + 4 streamed groups) + enc_t + transposes
    lstm_enct<<<304, 1024, 0, stream>>>(xproj, Wt2, b_hh, h0, c0, combined, hT, cT,
                                        enc_raw, We, be, enct,
                                        Wd, Wdt, W_out, WoT2);
    // 3) fused attention + logits (pipelined scores/ctx, fdot2 vocab)
    attn_logits<<<512, 512, 0, stream>>>(enct, combined, Wdt, bd, enc_raw,
                                         wa, ba, lens, WoT2, b_out, ctx_out, probs);
}

// Round 10
// 205.362 us; speedup vs baseline: 1.0208x; 1.0170x over previous
//
#include <hip/hip_runtime.h>
#include <hip/hip_fp16.h>
#include <math.h>

typedef unsigned int u32;
typedef unsigned short u16;

#define T_ 16
#define B_ 32
#define S_ 256
#define H_ 256
#define E_ 300
#define V_ 1000

typedef _Float16 h2_t __attribute__((ext_vector_type(2)));
typedef __fp16  fp16v2 __attribute__((ext_vector_type(2)));

__device__ __forceinline__ float fast_tanh(float x) {
    return 1.0f - 2.0f / (__expf(2.0f * x) + 1.0f);
}
__device__ __forceinline__ float fast_sigm(float x) {
    return 1.0f / (1.0f + __expf(-x));
}
__device__ __forceinline__ u32 pk2(float a, float b) {
    union { fp16v2 v; u32 u; } c; c.v = __builtin_amdgcn_cvt_pkrtz(a, b); return c.u;
}
__device__ __forceinline__ h2_t u2h2(u32 u) {
    union { u32 a; h2_t b; } c; c.a = u; return c.b;
}
__device__ __forceinline__ float dot2f16(u32 w, u32 h, float acc) {
#if __has_builtin(__builtin_amdgcn_fdot2)
    return __builtin_amdgcn_fdot2(u2h2(w), u2h2(h), acc, false);
#else
    h2_t wv = u2h2(w), hv = u2h2(h);
    return acc + (float)wv.x * (float)hv.x + (float)wv.y * (float)hv.y;
#endif
}

// ---------------------------------------------------------------------------
// Kernel 1: prep v6 (round-7 proven) — xproj GEMM 32x64 tiles + Whh->Wt2.
// ---------------------------------------------------------------------------
__global__ __launch_bounds__(256)
void prep_xproj(const float* __restrict__ emb, const int* __restrict__ tv,
                const float* __restrict__ W_ih, const float* __restrict__ b_ih,
                float* __restrict__ xproj,
                const float* __restrict__ Whh,  u32* __restrict__ Wt2)
{
    const int bid = blockIdx.x;
    const int tid = threadIdx.x;
    if (bid < 256) {
        __shared__ float As[32][33];
        __shared__ float Bs[32][64];
        const int bm = (bid >> 4) * 32;
        const int bn = (bid & 15) * 64;
        const int ty = tid >> 4;
        const int tx = tid & 15;
        const int alr = tid >> 3;
        const int alk = (tid & 7) * 4;
        const int blr = tid >> 2;
        const int blk = (tid & 3) * 8;

        const float* Ap = emb + (size_t)tv[bm + alr] * E_;
        const float* Bp = W_ih + (size_t)(bn + blr) * E_;

        float acc[2][4] = {};
        for (int k0 = 0; k0 < E_; k0 += 32) {
            int kb = k0 + alk;
            float4 a4;
            if (kb + 4 <= E_) {
                a4 = *(const float4*)(Ap + kb);
            } else {
                a4.x = (kb + 0 < E_) ? Ap[kb + 0] : 0.0f;
                a4.y = (kb + 1 < E_) ? Ap[kb + 1] : 0.0f;
                a4.z = (kb + 2 < E_) ? Ap[kb + 2] : 0.0f;
                a4.w = (kb + 3 < E_) ? Ap[kb + 3] : 0.0f;
            }
            As[alk + 0][alr] = a4.x; As[alk + 1][alr] = a4.y;
            As[alk + 2][alr] = a4.z; As[alk + 3][alr] = a4.w;

            int kbb = k0 + blk;
            float bv[8];
            if (kbb + 8 <= E_) {
                float4 p0 = *(const float4*)(Bp + kbb);
                float4 p1 = *(const float4*)(Bp + kbb + 4);
                bv[0]=p0.x; bv[1]=p0.y; bv[2]=p0.z; bv[3]=p0.w;
                bv[4]=p1.x; bv[5]=p1.y; bv[6]=p1.z; bv[7]=p1.w;
            } else {
                #pragma unroll
                for (int j = 0; j < 8; j++) bv[j] = (kbb + j < E_) ? Bp[kbb + j] : 0.0f;
            }
            #pragma unroll
            for (int j = 0; j < 8; j++) Bs[blk + j][blr] = bv[j];
            __syncthreads();
            #pragma unroll
            for (int kk = 0; kk < 32; kk++) {
                float ax = As[kk][ty * 2], ay = As[kk][ty * 2 + 1];
                float4 b = *(const float4*)&Bs[kk][tx * 4];
                acc[0][0] += ax*b.x; acc[0][1] += ax*b.y; acc[0][2] += ax*b.z; acc[0][3] += ax*b.w;
                acc[1][0] += ay*b.x; acc[1][1] += ay*b.y; acc[1][2] += ay*b.z; acc[1][3] += ay*b.w;
            }
            __syncthreads();
        }
        #pragma unroll
        for (int i = 0; i < 2; i++) {
            int m = bm + ty * 2 + i;
            #pragma unroll
            for (int j = 0; j < 4; j++) {
                int n = bn + tx * 4 + j;
                xproj[(size_t)m * 1024 + n] = acc[i][j] + b_ih[n];
            }
        }
        return;
    }
    // Whh transpose -> Wt2 uint4 [32][1024] (f16 pairs), bids 256..319
    __shared__ float tile[64][65];
    const int wv = tid >> 6;
    const int lane = tid & 63;
    int t = bid - 256;
    int r0 = (t >> 2) * 64, k0 = (t & 3) * 64;
    #pragma unroll 4
    for (int j = 0; j < 16; j++) {
        int row = wv * 16 + j;
        tile[row][lane] = Whh[(size_t)(r0 + row) * 256 + k0 + lane];
    }
    __syncthreads();
    #pragma unroll
    for (int it = 0; it < 2; it++) {
        int q = wv + 4 * it;
        uint4 val;
        val.x = pk2(tile[lane][8*q + 0], tile[lane][8*q + 1]);
        val.y = pk2(tile[lane][8*q + 2], tile[lane][8*q + 3]);
        val.z = pk2(tile[lane][8*q + 4], tile[lane][8*q + 5]);
        val.w = pk2(tile[lane][8*q + 6], tile[lane][8*q + 7]);
        ((uint4*)Wt2)[(size_t)((k0 >> 3) + q) * 1024 + r0 + lane] = val;
    }
}

// ---------------------------------------------------------------------------
// Kernel 2: lstm + enc_t + transposes (round-9 body, unchanged).
// ---------------------------------------------------------------------------
__global__ __launch_bounds__(1024)
__attribute__((amdgpu_waves_per_eu(4, 4)))
void lstm_enct(const float* __restrict__ xproj,   // [T,B,1024]
               const u32*   __restrict__ Wt2,     // uint4 [32][1024]
               const float* __restrict__ bhh,     // [1024]
               const float* __restrict__ h0, const float* __restrict__ c0,
               float* __restrict__ combined,      // [T,B,512] second half
               float* __restrict__ hT, float* __restrict__ cT,
               const float* __restrict__ enc_raw, // [8192,256]
               const float* __restrict__ We,      // [256,256]
               const float* __restrict__ be,
               float* __restrict__ enct,          // [8192,256]
               const float* __restrict__ Wd,   float* __restrict__ Wdt,
               const float* __restrict__ W_out, u32* __restrict__ WoT2)
{
    const int bid = blockIdx.x;
    const int tid = threadIdx.x;
    __shared__ __align__(16) u32 smem[38272];

    if (bid < 32) {
        float* zs = (float*)smem;            // [1024]
        float* cs = (float*)(smem + 1024);   // [256]
        u32*   hp = smem + 1280;             // [128]
        u32*   wlds = smem + 1408;           // [32][1024] dword-sliced (8 groups)
        float* hsave = (float*)(smem + 34176); // [16][256]
        const int b = bid;
        const int r = tid;
        if (tid < 256) {
            float h0v = h0[b * 256 + tid];
            cs[tid] = c0[b * 256 + tid];
            float hpart = __shfl_xor(h0v, 1, 64);
            if (!(tid & 1)) hp[tid >> 1] = pk2(h0v, hpart);
        }
        const float bh = bhh[r];
        const uint4* wp4 = (const uint4*)Wt2 + r;

        // groups 12..31 -> registers (80 VGPR)
        uint4 wreg[20];
        #pragma unroll
        for (int j = 0; j < 20; j++) wreg[j] = wp4[(size_t)(12 + j) * 1024];
        // groups 4..11 -> LDS ([dw][r]: lane stride 4B, no conflict)
        #pragma unroll
        for (int j = 0; j < 8; j++) {
            uint4 w = wp4[(size_t)(4 + j) * 1024];
            wlds[(j * 4 + 0) * 1024 + r] = w.x;
            wlds[(j * 4 + 1) * 1024 + r] = w.y;
            wlds[(j * 4 + 2) * 1024 + r] = w.z;
            wlds[(j * 4 + 3) * 1024 + r] = w.w;
        }
        __syncthreads();

        for (int t = 0; t < T_; t++) {
            float xp = xproj[((size_t)t * B_ + b) * 1024 + r];
            float acc = 0.0f;
            const uint4* hp4 = (const uint4*)hp;
            #pragma unroll
            for (int i = 0; i < 4; i++) {
                uint4 hv = hp4[i];
                uint4 w  = wp4[(size_t)i * 1024];
                acc = dot2f16(w.x, hv.x, acc);
                acc = dot2f16(w.y, hv.y, acc);
                acc = dot2f16(w.z, hv.z, acc);
                acc = dot2f16(w.w, hv.w, acc);
            }
            #pragma unroll
            for (int j = 0; j < 8; j++) {
                uint4 hv = hp4[4 + j];
                u32 w0 = wlds[(j * 4 + 0) * 1024 + r];
                u32 w1 = wlds[(j * 4 + 1) * 1024 + r];
                u32 w2 = wlds[(j * 4 + 2) * 1024 + r];
                u32 w3 = wlds[(j * 4 + 3) * 1024 + r];
                acc = dot2f16(w0, hv.x, acc);
                acc = dot2f16(w1, hv.y, acc);
                acc = dot2f16(w2, hv.z, acc);
                acc = dot2f16(w3, hv.w, acc);
            }
            #pragma unroll
            for (int j = 0; j < 20; j++) {
                uint4 hv = hp4[12 + j];
                acc = dot2f16(wreg[j].x, hv.x, acc);
                acc = dot2f16(wreg[j].y, hv.y, acc);
                acc = dot2f16(wreg[j].z, hv.z, acc);
                acc = dot2f16(wreg[j].w, hv.w, acc);
            }
            zs[r] = xp + bh + acc;
            __syncthreads();

            if (tid < 256) {
                float ig = fast_sigm(zs[tid]);
                float fg = fast_sigm(zs[256 + tid]);
                float gg = fast_tanh(zs[512 + tid]);
                float og = fast_sigm(zs[768 + tid]);
                float c = fg * cs[tid] + ig * gg;
                float h = og * fast_tanh(c);
                cs[tid] = c;
                hsave[(t << 8) + tid] = h;
                float hpart = __shfl_xor(h, 1, 64);
                if (!(tid & 1)) hp[tid >> 1] = pk2(h, hpart);
            }
            __syncthreads();
        }

        #pragma unroll
        for (int i = 0; i < 4; i++) {
            int idx = tid + i * 1024;
            int t = idx >> 8, h = idx & 255;
            combined[((size_t)t * B_ + b) * 512 + 256 + h] = hsave[idx];
        }
        if (tid < 256) {
            hT[b * 256 + tid] = hsave[(15 << 8) + tid];
            cT[b * 256 + tid] = cs[tid];
        }
    } else if (bid < 160) {
        float (*As2)[132] = (float (*)[132])smem;
        float (*Bs2)[132] = (float (*)[132])(smem + 4224);
        const int tile = bid - 32;
        const int bm = (tile >> 1) * 128;
        const int bn = (tile & 1) * 128;
        const int tx = tid & 31, ty = tid >> 5;
        const int lr = tid >> 3;
        const int lk = (tid & 7) * 4;

        const float* Ap = enc_raw + (size_t)(bm + lr) * 256;
        const float* Bp = We + (size_t)(bn + lr) * 256;
        float acc[4][4] = {};

        for (int k0 = 0; k0 < 256; k0 += 32) {
            float4 a4 = *(const float4*)(Ap + k0 + lk);
            float4 b4 = *(const float4*)(Bp + k0 + lk);
            As2[lk + 0][lr] = a4.x; As2[lk + 1][lr] = a4.y;
            As2[lk + 2][lr] = a4.z; As2[lk + 3][lr] = a4.w;
            Bs2[lk + 0][lr] = b4.x; Bs2[lk + 1][lr] = b4.y;
            Bs2[lk + 2][lr] = b4.z; Bs2[lk + 3][lr] = b4.w;
            __syncthreads();
            #pragma unroll
            for (int kk = 0; kk < 32; kk++) {
                float4 a = *(const float4*)&As2[kk][ty * 4];
                float4 b = *(const float4*)&Bs2[kk][tx * 4];
                acc[0][0] += a.x*b.x; acc[0][1] += a.x*b.y; acc[0][2] += a.x*b.z; acc[0][3] += a.x*b.w;
                acc[1][0] += a.y*b.x; acc[1][1] += a.y*b.y; acc[1][2] += a.y*b.z; acc[1][3] += a.y*b.w;
                acc[2][0] += a.z*b.x; acc[2][1] += a.z*b.y; acc[2][2] += a.z*b.z; acc[2][3] += a.z*b.w;
                acc[3][0] += a.w*b.x; acc[3][1] += a.w*b.y; acc[3][2] += a.w*b.z; acc[3][3] += a.w*b.w;
            }
            __syncthreads();
        }
        #pragma unroll
        for (int i = 0; i < 4; i++) {
            int m = bm + ty * 4 + i;
            #pragma unroll
            for (int j = 0; j < 4; j++) {
                int n = bn + tx * 4 + j;
                enct[(size_t)m * 256 + n] = acc[i][j] + be[n];
            }
        }
    } else if (bid < 176) {
        // Wd transpose: fp32 float4 [64][256]
        float (*tile)[65] = (float (*)[65])smem;
        const int w = tid >> 6;
        const int lane = tid & 63;
        int t = bid - 160;
        int h0 = (t >> 2) * 64, k0 = (t & 3) * 64;
        #pragma unroll
        for (int j = 0; j < 4; j++) {
            int row = w * 4 + j;
            tile[row][lane] = Wd[(size_t)(h0 + row) * 256 + k0 + lane];
        }
        __syncthreads();
        {
            int q = w;
            float4 v;
            v.x = tile[lane][4*q + 0];
            v.y = tile[lane][4*q + 1];
            v.z = tile[lane][4*q + 2];
            v.w = tile[lane][4*q + 3];
            ((float4*)Wdt)[(size_t)((k0 >> 2) + q) * 256 + h0 + lane] = v;
        }
    } else {
        // W_out -> WoT2 f16-pair transpose: uint4 [64 kq8][1000 v]
        float (*tile)[65] = (float (*)[65])smem;
        const int w = tid >> 6;        // 0..15
        const int lane = tid & 63;
        int t = bid - 176;             // 0..127
        int v0 = (t >> 3) * 64, k0 = (t & 7) * 64;
        #pragma unroll
        for (int j = 0; j < 4; j++) {
            int row = w * 4 + j;
            int v = v0 + row;
            tile[row][lane] = (v < V_) ? W_out[(size_t)v * 512 + k0 + lane] : 0.0f;
        }
        __syncthreads();
        if (w < 8) {
            int q = w;                 // kq8 within tile, 0..7
            int v = v0 + lane;
            if (v < V_) {
                uint4 val;
                val.x = pk2(tile[lane][8*q + 0], tile[lane][8*q + 1]);
                val.y = pk2(tile[lane][8*q + 2], tile[lane][8*q + 3]);
                val.z = pk2(tile[lane][8*q + 4], tile[lane][8*q + 5]);
                val.w = pk2(tile[lane][8*q + 6], tile[lane][8*q + 7]);
                ((uint4*)WoT2)[(size_t)((k0 >> 3) + q) * 1000 + v] = val;
            }
        }
    }
}

// ---------------------------------------------------------------------------
// Kernel 3: attention through ctx. Round-10: the vocab phase is SPLIT OUT.
// Budget model: each of 2 co-resident blocks streamed the full 1 MB WoT2
// through its CU's L1 (2 MB/CU = ~13.6 us) — the largest item in attn's
// 55 us, insensitive to instruction count (r8 proved). This kernel now ends
// at ctx and stores the packed f16-pair row (crow_pk) for the vocab kernel.
// All retained phases byte-identical to round 9.
// ---------------------------------------------------------------------------
__global__ __launch_bounds__(512)
void attn_logits(const float* __restrict__ enct,        // [S,B,H]
                 const float* __restrict__ combined_in, // [T,B,512] (2nd half)
                 const float* __restrict__ Wdt,         // float4 [64][256]
                 const float* __restrict__ bd,
                 const float* __restrict__ enc_raw,     // [S,B,H]
                 const float* __restrict__ wa, const float* __restrict__ ba,
                 const int* __restrict__ lens,
                 float* __restrict__ ctx_out,           // [B,T,H] (d_out)
                 u32* __restrict__ crow_pk_ws)          // [512][256] f16-pair
{
    const int bid = blockIdx.x;
    const int b = bid & 31;          // XCD swizzle
    const int t = bid >> 5;
    const int tid = threadIdx.x;
    const int wv = tid >> 6, lane = tid & 63;
    __shared__ float ds[256], was[256], sc[256];
    __shared__ float crow[512];
    __shared__ float tmp2[512];
    __shared__ float red[8], red2[8];

    if (tid < 256) {
        crow[256 + tid] = combined_in[((size_t)t * B_ + b) * 512 + 256 + tid];
        was[tid] = wa[tid];
    }
    const int len = lens[b];
    const float bav = ba[0];
    __syncthreads();

    {
        const int h   = tid & 255;
        const int kq0 = (tid >> 8) * 32;
        float acc = 0.0f;
        const float4* wp = (const float4*)Wdt + h;
        #pragma unroll 8
        for (int kq = kq0; kq < kq0 + 32; kq++) {
            float4 w = wp[(size_t)kq * 256];
            float4 c = *(const float4*)&crow[256 + kq * 4];
            acc += w.x * c.x;
            acc += w.y * c.y;
            acc += w.z * c.z;
            acc += w.w * c.w;
        }
        tmp2[tid] = acc;
    }
    __syncthreads();
    if (tid < 256) ds[tid] = bd[tid] + tmp2[tid] + tmp2[tid + 256];
    __syncthreads();

    // scores: software-pipelined row loads (round-9 proven, bit-identical)
    {
        float c0 = 0.f, c1 = 0.f, c2 = 0.f, c3 = 0.f;
        if (wv < len) {
            const float* er = enct + ((size_t)wv * B_ + b) * 256;
            c0 = er[lane]; c1 = er[lane + 64]; c2 = er[lane + 128]; c3 = er[lane + 192];
        }
        for (int s = wv; s < len; s += 8) {
            int sn = s + 8;
            float n0 = 0.f, n1 = 0.f, n2 = 0.f, n3 = 0.f;
            if (sn < len) {
                const float* ern = enct + ((size_t)sn * B_ + b) * 256;
                n0 = ern[lane]; n1 = ern[lane + 64]; n2 = ern[lane + 128]; n3 = ern[lane + 192];
            }
            float sum = 0.0f;
            sum += fast_tanh(c0 + ds[lane]) * was[lane];
            sum += fast_tanh(c1 + ds[lane + 64]) * was[lane + 64];
            sum += fast_tanh(c2 + ds[lane + 128]) * was[lane + 128];
            sum += fast_tanh(c3 + ds[lane + 192]) * was[lane + 192];
            #pragma unroll
            for (int off = 32; off >= 1; off >>= 1) sum += __shfl_xor(sum, off, 64);
            if (lane == 0) sc[s] = sum + bav;
            c0 = n0; c1 = n1; c2 = n2; c3 = n3;
        }
    }
    __syncthreads();

    float x = (tid < len) ? sc[tid] : -INFINITY;
    float m = x;
    #pragma unroll
    for (int off = 32; off >= 1; off >>= 1) m = fmaxf(m, __shfl_xor(m, off, 64));
    if (lane == 0) red[wv] = m;
    __syncthreads();
    m = red[0];
    #pragma unroll
    for (int i = 1; i < 8; i++) m = fmaxf(m, red[i]);
    float e = __expf(x - m);
    float ssum = e;
    #pragma unroll
    for (int off = 32; off >= 1; off >>= 1) ssum += __shfl_xor(ssum, off, 64);
    if (lane == 0) red2[wv] = ssum;
    __syncthreads();
    ssum = red2[0] + red2[1] + red2[2] + red2[3] + red2[4] + red2[5] + red2[6] + red2[7];
    if (tid < 256) sc[tid] = e / ssum;
    __syncthreads();

    {
        const int h  = tid & 255;
        const int sg = tid >> 8;
        const int mid = (len + 1) >> 1;
        const int s0 = sg ? mid : 0;
        const int s1 = sg ? len : mid;
        float cacc = 0.0f;
        const float* eb = enc_raw + (size_t)b * 256 + h;
        #pragma unroll 8
        for (int s = s0; s < s1; s++) cacc += sc[s] * eb[(size_t)s * (B_ * H_)];
        tmp2[tid] = cacc;
    }
    __syncthreads();
    if (tid < 256) {
        float ctx = tmp2[tid] + tmp2[tid + 256];
        ctx_out[((size_t)b * T_ + t) * 256 + tid] = ctx;
        crow[tid] = ctx;
    }
    __syncthreads();
    // pack (ctx | h) into f16-pairs and hand off to the vocab kernel
    if (tid < 256)
        crow_pk_ws[(size_t)(t * B_ + b) * 256 + tid] = pk2(crow[2 * tid], crow[2 * tid + 1]);
}

// ---------------------------------------------------------------------------
// Kernel 4 (NEW): vocab logits + softmax, 2 rows per block (grid 256 =
// 1 block/CU). WoT2 is streamed ONCE per block and used for both rows:
// L1 traffic for the vocab matmul halves (2 MB/CU -> 1 MB/CU). Row-batching
// is safe here (almost no barriers — the r3/r4 failure was barrier-bound).
// Per-row fdot2 k-order and the 8-wave softmax tree are verbatim round-9
// -> probs bit-identical.
// ---------------------------------------------------------------------------
__global__ __launch_bounds__(512)
void vocab_probs(const u32* __restrict__ crow_pk_ws,   // [512][256]
                 const u32* __restrict__ WoT2,         // uint4 [64][1000]
                 const float* __restrict__ b_out,      // [1000]
                 float* __restrict__ probs)            // [T,B,V]
{
    const int bid = blockIdx.x;      // 0..255
    const int r0 = bid * 2;
    const int tid = threadIdx.x;
    const int wv = tid >> 6, lane = tid & 63;
    __shared__ u32 pk[2][256];
    __shared__ float lrow[2][1000];
    __shared__ float red[8], red2[8];

    {
        int rr = tid >> 8, idx = tid & 255;
        pk[rr][idx] = crow_pk_ws[(size_t)(r0 + rr) * 256 + idx];
    }
    __syncthreads();

    if (tid < 500) {
        const int v0 = tid * 2;
        const float b0v = b_out[v0], b1v = b_out[v0 + 1];
        float a00 = b0v, a01 = b1v;
        float a10 = b0v, a11 = b1v;
        const uint4* wp  = (const uint4*)WoT2 + v0;
        const uint4* h0p = (const uint4*)pk[0];
        const uint4* h1p = (const uint4*)pk[1];
        #pragma unroll 4
        for (int kq = 0; kq < 64; kq++) {
            uint4 w0 = wp[(size_t)kq * 1000];
            uint4 w1 = wp[(size_t)kq * 1000 + 1];
            uint4 hv0 = h0p[kq];
            uint4 hv1 = h1p[kq];
            a00 = dot2f16(w0.x, hv0.x, a00);
            a00 = dot2f16(w0.y, hv0.y, a00);
            a00 = dot2f16(w0.z, hv0.z, a00);
            a00 = dot2f16(w0.w, hv0.w, a00);
            a01 = dot2f16(w1.x, hv0.x, a01);
            a01 = dot2f16(w1.y, hv0.y, a01);
            a01 = dot2f16(w1.z, hv0.z, a01);
            a01 = dot2f16(w1.w, hv0.w, a01);
            a10 = dot2f16(w0.x, hv1.x, a10);
            a10 = dot2f16(w0.y, hv1.y, a10);
            a10 = dot2f16(w0.z, hv1.z, a10);
            a10 = dot2f16(w0.w, hv1.w, a10);
            a11 = dot2f16(w1.x, hv1.x, a11);
            a11 = dot2f16(w1.y, hv1.y, a11);
            a11 = dot2f16(w1.z, hv1.z, a11);
            a11 = dot2f16(w1.w, hv1.w, a11);
        }
        lrow[0][v0] = a00; lrow[0][v0 + 1] = a01;
        lrow[1][v0] = a10; lrow[1][v0 + 1] = a11;
    }
    __syncthreads();

    #pragma unroll
    for (int ti = 0; ti < 2; ti++) {
        const int row = r0 + ti;
        float v0v = -INFINITY, v1v = -INFINITY;
        if (tid < 500) { v0v = lrow[ti][tid * 2]; v1v = lrow[ti][tid * 2 + 1]; }
        float mx = fmaxf(v0v, v1v);
        #pragma unroll
        for (int off = 32; off >= 1; off >>= 1) mx = fmaxf(mx, __shfl_xor(mx, off, 64));
        if (lane == 0) red[wv] = mx;
        __syncthreads();
        mx = red[0];
        #pragma unroll
        for (int i = 1; i < 8; i++) mx = fmaxf(mx, red[i]);
        float e0 = __expf(v0v - mx), e1 = __expf(v1v - mx);
        float s2 = e0 + e1;
        #pragma unroll
        for (int off = 32; off >= 1; off >>= 1) s2 += __shfl_xor(s2, off, 64);
        if (lane == 0) red2[wv] = s2;
        __syncthreads();
        s2 = red2[0] + red2[1] + red2[2] + red2[3] + red2[4] + red2[5] + red2[6] + red2[7];
        float inv = 1.0f / s2;
        if (tid < 500) {
            float2 pv = make_float2(e0 * inv, e1 * inv);
            *(float2*)&probs[(size_t)row * V_ + tid * 2] = pv;
        }
        __syncthreads();
    }
}

extern "C" void kernel_launch(void* const* d_in, const int* in_sizes, int n_in,
                              void* d_out, int out_size, void* d_ws, size_t ws_size,
                              hipStream_t stream) {
    const int*   tv       = (const int*)d_in[0];
    const float* h0       = (const float*)d_in[1];
    const float* c0       = (const float*)d_in[2];
    const float* enc_raw  = (const float*)d_in[3];
    const int*   lens     = (const int*)d_in[4];
    const float* emb      = (const float*)d_in[5];
    const float* W_ih     = (const float*)d_in[6];
    const float* W_hh     = (const float*)d_in[7];
    const float* b_ih     = (const float*)d_in[8];
    const float* b_hh     = (const float*)d_in[9];
    const float* We       = (const float*)d_in[10];
    const float* be       = (const float*)d_in[11];
    const float* Wd       = (const float*)d_in[12];
    const float* bd       = (const float*)d_in[13];
    const float* wa       = (const float*)d_in[14];
    const float* ba       = (const float*)d_in[15];
    const float* W_out    = (const float*)d_in[16];
    const float* b_out    = (const float*)d_in[17];

    // workspace layout (fp32 words)
    float* ws       = (float*)d_ws;
    float* enct     = ws;                       // [8192,256]  2,097,152
    float* xproj    = ws + 2097152;             // [512,1024]    524,288
    float* Wdt      = ws + 2621440;             // float4 [64][256]  65,536 f
    u32*   WoT2     = (u32*)(ws + 2752512);     // uint4 [64][1000] f16-pair, 1 MB
    float* combined = ws + 3264512;             // [512,512]     262,144
    u32*   Wt2      = (u32*)(ws + 3526656);     // uint4 [32][1024]  512 KB
    // crow_pk reuses xproj (dead after lstm): 512 rows x 256 u32 = 512 KB
    u32*   crow_pk  = (u32*)xproj;

    // d_out layout (fp32): probs [T,B,V], hT, cT, ctx [B,T,H]
    float* out      = (float*)d_out;
    float* probs    = out;
    float* hT       = out + 512000;
    float* cT       = out + 520192;
    float* ctx_out  = out + 528384;

    // 1) xproj GEMM (32x64 tiles) + Whh->Wt2 transpose
    prep_xproj<<<320, 256, 0, stream>>>(emb, tv, W_ih, b_ih, xproj, W_hh, Wt2);
    // 2) LSTM (20 reg + 8 LDS + 4 streamed groups) + enc_t + transposes
    lstm_enct<<<304, 1024, 0, stream>>>(xproj, Wt2, b_hh, h0, c0, combined, hT, cT,
                                        enc_raw, We, be, enct,
                                        Wd, Wdt, W_out, WoT2);
    // 3) attention through ctx; hands off packed rows
    attn_logits<<<512, 512, 0, stream>>>(enct, combined, Wdt, bd, enc_raw,
                                         wa, ba, lens, ctx_out, crow_pk);
    // 4) vocab logits + softmax, 2 rows/block (WoT2 streamed once per block)
    vocab_probs<<<256, 512, 0, stream>>>(crow_pk, WoT2, b_out, probs);
}